// Round 1
// baseline (281.184 us; speedup 1.0000x reference)
//
#include <hip/hip_runtime.h>
#include <hip/hip_bf16.h>
#include <math.h>

#define B_ 4
#define N_ 4096
#define D_ 256
#define H_ 8
#define HD_ 32
#define TOKENS (B_ * N_)   // 16384
#define EPSF 1e-9f

__device__ __forceinline__ float elu1(float x) { return x > 0.f ? x + 1.f : __expf(x); }

// ---------------- bias[row] = mean(prior[row][:]), row = b*N + n ----------------
__global__ __launch_bounds__(256) void k_bias(const float* __restrict__ prior,
                                              float* __restrict__ bias) {
    const int row = blockIdx.x;
    const int t = threadIdx.x;
    const float4* p = (const float4*)(prior + (size_t)row * N_);
    float s = 0.f;
#pragma unroll
    for (int j = 0; j < 4; ++j) {
        float4 v = p[(size_t)j * 256 + t];
        s += v.x + v.y + v.z + v.w;
    }
#pragma unroll
    for (int off = 32; off > 0; off >>= 1) s += __shfl_down(s, off, 64);
    __shared__ float red[4];
    if ((t & 63) == 0) red[t >> 6] = s;
    __syncthreads();
    if (t == 0) bias[row] = (red[0] + red[1] + red[2] + red[3]) * (1.0f / N_);
}

// ---------------- Y[M x 256] = X[M x 256] @ W[256 x 256 (row=out col e, col=k)]^T ----------------
// MODE 0: q = elu1(acc + bias[row])   MODE 1: k = elu1(acc)
// MODE 2: v = elu1(acc + bvec[col])   MODE 3: out = acc + bvec[col]
template <int MODE>
__global__ __launch_bounds__(256) void k_gemm(const float* __restrict__ X,
                                              const float* __restrict__ W,
                                              const float* __restrict__ bvec,
                                              const float* __restrict__ bscal,
                                              float* __restrict__ Y) {
    // transposed LDS tiles: [k][row/col] so compute reads are ds_read_b128
    __shared__ float AsT[16][68];
    __shared__ float BsT[16][68];
    const int t = threadIdx.x;
    const int tx = t & 15, ty = t >> 4;
    const int rowBase = blockIdx.x * 64;
    const int colBase = blockIdx.y * 64;
    const int lr = t >> 2;          // 0..63 (staging row)
    const int lc = (t & 3) * 4;     // 0,4,8,12 (staging k-chunk)
    const float* xg = X + (size_t)(rowBase + lr) * D_ + lc;
    const float* wg = W + (size_t)(colBase + lr) * D_ + lc;
    float c[4][4] = {};
    for (int kt = 0; kt < D_; kt += 16) {
        const float4 xa = *(const float4*)(xg + kt);
        const float4 wb = *(const float4*)(wg + kt);
        __syncthreads();
        AsT[lc + 0][lr] = xa.x; AsT[lc + 1][lr] = xa.y;
        AsT[lc + 2][lr] = xa.z; AsT[lc + 3][lr] = xa.w;
        BsT[lc + 0][lr] = wb.x; BsT[lc + 1][lr] = wb.y;
        BsT[lc + 2][lr] = wb.z; BsT[lc + 3][lr] = wb.w;
        __syncthreads();
#pragma unroll
        for (int k = 0; k < 16; ++k) {
            const float4 a4 = *(const float4*)&AsT[k][ty * 4];
            const float4 b4 = *(const float4*)&BsT[k][tx * 4];
            const float a[4] = {a4.x, a4.y, a4.z, a4.w};
            const float b[4] = {b4.x, b4.y, b4.z, b4.w};
#pragma unroll
            for (int i = 0; i < 4; ++i)
#pragma unroll
                for (int j = 0; j < 4; ++j)
                    c[i][j] = fmaf(a[i], b[j], c[i][j]);
        }
    }
#pragma unroll
    for (int i = 0; i < 4; ++i) {
        const int r = rowBase + ty * 4 + i;
        float4 o;
        float* op = &o.x;
#pragma unroll
        for (int j = 0; j < 4; ++j) {
            float vv = c[i][j];
            const int col = colBase + tx * 4 + j;
            if (MODE == 0) vv = elu1(vv + bscal[r]);
            else if (MODE == 1) vv = elu1(vv);
            else if (MODE == 2) vv = elu1(vv + bvec[col]);
            else vv = vv + bvec[col];
            op[j] = vv;
        }
        *(float4*)&Y[(size_t)r * D_ + colBase + tx * 4] = o;
    }
}

// ---------------- kv[b,h,m,d] = sum_n v[b,n,h,m]*k[b,n,h,d];  ksum[b,h,d] = sum_n k ----------------
__global__ __launch_bounds__(256) void k_kvsum(const float* __restrict__ kmat,
                                               const float* __restrict__ vmat,
                                               float* __restrict__ kv,
                                               float* __restrict__ ksum) {
    const int bh = blockIdx.x;           // b*8+h
    const int b = bh >> 3, h = bh & 7;
    const int CH = gridDim.y;
    const int rows = N_ / CH;
    const int tok0 = b * N_ + blockIdx.y * rows;
    __shared__ float kt_[64][32];
    __shared__ float vt_[64][32];
    const int t = threadIdx.x;
    const int m = t >> 3;                // 0..31 (value dim owned)
    const int lvec = (t & 7) * 4;        // 0..28 (key dim chunk)
    float4 acc = {0.f, 0.f, 0.f, 0.f};
    float4 sk = {0.f, 0.f, 0.f, 0.f};
    for (int r0 = 0; r0 < rows; r0 += 64) {
        __syncthreads();
#pragma unroll
        for (int half = 0; half < 2; ++half) {
            const int rr = (t >> 3) + half * 32;
            const size_t g = (size_t)(tok0 + r0 + rr) * D_ + h * HD_ + lvec;
            *(float4*)&kt_[rr][lvec] = *(const float4*)(kmat + g);
            *(float4*)&vt_[rr][lvec] = *(const float4*)(vmat + g);
        }
        __syncthreads();
#pragma unroll 4
        for (int r = 0; r < 64; ++r) {
            const float vv = vt_[r][m];
            const float4 kk = *(const float4*)&kt_[r][lvec];
            acc.x = fmaf(vv, kk.x, acc.x);
            acc.y = fmaf(vv, kk.y, acc.y);
            acc.z = fmaf(vv, kk.z, acc.z);
            acc.w = fmaf(vv, kk.w, acc.w);
            sk.x += kk.x; sk.y += kk.y; sk.z += kk.z; sk.w += kk.w;
        }
    }
    float* kvp = kv + ((size_t)bh * HD_ + m) * HD_ + lvec;
    atomicAdd(kvp + 0, acc.x);
    atomicAdd(kvp + 1, acc.y);
    atomicAdd(kvp + 2, acc.z);
    atomicAdd(kvp + 3, acc.w);
    if (m == 0) {
        float* kp = ksum + (size_t)bh * HD_ + lvec;
        atomicAdd(kp + 0, sk.x);
        atomicAdd(kp + 1, sk.y);
        atomicAdd(kp + 2, sk.z);
        atomicAdd(kp + 3, sk.w);
    }
}

// ---------------- attn[tok, h*32+m] = (q_h . kv[h,m,:]) / (q_h . ksum_h + eps), masked ----------------
__global__ __launch_bounds__(256) void k_attn(const float* __restrict__ q,
                                              const float* __restrict__ kv,
                                              const float* __restrict__ ksum,
                                              float* __restrict__ attn) {
    const int tok = blockIdx.x;
    const int b = tok >> 12;             // 4096 tokens per batch
    const int t = threadIdx.x;
    __shared__ float qs[256];
    qs[t] = q[(size_t)tok * D_ + t];
    __syncthreads();
    const int h = t >> 5, m = t & 31;
    const float* kvp = kv + ((size_t)(b * H_ + h) * HD_ + m) * HD_;
    const float* ksp = ksum + (size_t)(b * H_ + h) * HD_;
    float dot = 0.f, zden = 0.f;
    bool allz = true;
#pragma unroll
    for (int d = 0; d < HD_; ++d) {
        const float qd = qs[h * HD_ + d];
        dot = fmaf(qd, kvp[d], dot);
        zden = fmaf(qd, ksp[d], zden);
        allz = allz && (qd == 0.f);
    }
    const float val = allz ? 0.f : dot / (zden + EPSF);
    attn[(size_t)tok * D_ + t] = val;
}

extern "C" void kernel_launch(void* const* d_in, const int* in_sizes, int n_in,
                              void* d_out, int out_size, void* d_ws, size_t ws_size,
                              hipStream_t stream) {
    const float* x     = (const float*)d_in[0];
    const float* prior = (const float*)d_in[1];
    const float* Wq    = (const float*)d_in[2];
    const float* Wk    = (const float*)d_in[3];
    const float* Wv    = (const float*)d_in[4];
    const float* bv    = (const float*)d_in[5];
    const float* Wo    = (const float*)d_in[6];
    const float* bo    = (const float*)d_in[7];
    float* out = (float*)d_out;

    // workspace layout (floats): bias | q | k | v | kv | ksum ; attn aliases k
    float* ws   = (float*)d_ws;
    float* bias = ws;                              // 16384
    float* qb   = ws + 16384;                      // 16384*256
    float* kb   = qb + (size_t)TOKENS * D_;
    float* vb   = kb + (size_t)TOKENS * D_;
    float* kvb  = vb + (size_t)TOKENS * D_;        // 32*32*32 = 32768
    float* ksb  = kvb + 32768;                     // 1024
    float* attnb = kb;                             // k dead after k_kvsum

    k_bias<<<TOKENS, 256, 0, stream>>>(prior, bias);

    dim3 gg(TOKENS / 64, D_ / 64);
    k_gemm<0><<<gg, 256, 0, stream>>>(x, Wq, nullptr, bias, qb);
    k_gemm<1><<<gg, 256, 0, stream>>>(x, Wk, nullptr, nullptr, kb);
    k_gemm<2><<<gg, 256, 0, stream>>>(x, Wv, bv, nullptr, vb);

    hipMemsetAsync(kvb, 0, (32768 + 1024) * sizeof(float), stream);
    k_kvsum<<<dim3(32, 8), 256, 0, stream>>>(kb, vb, kvb, ksb);

    k_attn<<<TOKENS, 256, 0, stream>>>(qb, kvb, ksb, attnb);

    k_gemm<3><<<gg, 256, 0, stream>>>(attnb, Wo, bo, nullptr, out);
}

// Round 2
// 198.179 us; speedup vs baseline: 1.4188x; 1.4188x over previous
//
#include <hip/hip_runtime.h>
#include <hip/hip_bf16.h>
#include <math.h>

#define B_ 4
#define N_ 4096
#define D_ 256
#define H_ 8
#define HD_ 32
#define TOKENS (B_ * N_)   // 16384
#define EPSF 1e-9f

typedef __bf16 bf16x8 __attribute__((ext_vector_type(8)));
typedef float f32x4 __attribute__((ext_vector_type(4)));
typedef ushort ushort8_t __attribute__((ext_vector_type(8)));

__device__ __forceinline__ float elu1(float x) { return x > 0.f ? x + 1.f : __expf(x); }

__device__ __forceinline__ ushort f2bf(float f) {
    __hip_bfloat16 h = __float2bfloat16(f);
    return *reinterpret_cast<ushort*>(&h);
}
__device__ __forceinline__ float bf2f(ushort u) {
    __hip_bfloat16 h = *reinterpret_cast<__hip_bfloat16*>(&u);
    return __bfloat162float(h);
}

#define GLOAD_LDS16(g, l)                                                              \
    __builtin_amdgcn_global_load_lds((__attribute__((address_space(1))) const void*)(g), \
                                     (__attribute__((address_space(3))) void*)(l), 16, 0, 0)

// ---------------- fp32 -> bf16 convert, 8 elements/thread ----------------
__global__ __launch_bounds__(256) void k_cvt(const float* __restrict__ src,
                                             ushort* __restrict__ dst, int n8) {
    const int i = blockIdx.x * 256 + threadIdx.x;
    if (i >= n8) return;
    const float4* s = (const float4*)src + (size_t)i * 2;
    const float4 a = s[0], b = s[1];
    ushort8_t o;
    o[0] = f2bf(a.x); o[1] = f2bf(a.y); o[2] = f2bf(a.z); o[3] = f2bf(a.w);
    o[4] = f2bf(b.x); o[5] = f2bf(b.y); o[6] = f2bf(b.z); o[7] = f2bf(b.w);
    *((ushort8_t*)dst + i) = o;
}

// ---------------- all four W matrices -> bf16, concatenated ----------------
__global__ __launch_bounds__(256) void k_cvt_w(const float* __restrict__ Wq,
                                               const float* __restrict__ Wk,
                                               const float* __restrict__ Wv,
                                               const float* __restrict__ Wo,
                                               ushort* __restrict__ dst) {
    const int i = blockIdx.x * 256 + threadIdx.x;  // 32768 threads x 8 els
    const int sel = i >> 13;
    const float* src = sel == 0 ? Wq : sel == 1 ? Wk : sel == 2 ? Wv : Wo;
    const int j = i & 8191;
    const float4* s = (const float4*)src + (size_t)j * 2;
    const float4 a = s[0], b = s[1];
    ushort8_t o;
    o[0] = f2bf(a.x); o[1] = f2bf(a.y); o[2] = f2bf(a.z); o[3] = f2bf(a.w);
    o[4] = f2bf(b.x); o[5] = f2bf(b.y); o[6] = f2bf(b.z); o[7] = f2bf(b.w);
    *((ushort8_t*)dst + i) = o;
}

// ---------------- bias[row] = mean(prior[row][:]) ----------------
__global__ __launch_bounds__(256) void k_bias(const float* __restrict__ prior,
                                              float* __restrict__ bias) {
    const int row = blockIdx.x;
    const int t = threadIdx.x;
    const float4* p = (const float4*)(prior + (size_t)row * N_);
    float s = 0.f;
#pragma unroll
    for (int j = 0; j < 4; ++j) {
        float4 v = p[(size_t)j * 256 + t];
        s += v.x + v.y + v.z + v.w;
    }
#pragma unroll
    for (int off = 32; off > 0; off >>= 1) s += __shfl_down(s, off, 64);
    __shared__ float red[4];
    if ((t & 63) == 0) red[t >> 6] = s;
    __syncthreads();
    if (t == 0) bias[row] = (red[0] + red[1] + red[2] + red[3]) * (1.0f / N_);
}

// ---------------- bf16 MFMA GEMM: Y[M x 256] = A[M x 256] @ W[256(e) x 256(k)]^T ----
// 128x128 tile, BK=32, 4 waves (2x2), mfma_f32_16x16x32_bf16, global_load_lds staging.
// MODE 0: q = elu1(acc + bscal[row])  -> float
// MODE 1: k = elu1(acc)               -> bf16
// MODE 2: v = elu1(acc + bvec[col])   -> bf16
// MODE 3: out = acc + bvec[col]       -> float
template <int MODE>
__global__ __launch_bounds__(256) void k_mfma_gemm(const ushort* __restrict__ A,
                                                   const ushort* __restrict__ Wb,
                                                   const float* __restrict__ bvec,
                                                   const float* __restrict__ bscal,
                                                   void* __restrict__ Yv) {
    __shared__ ushort As[128 * 32];
    __shared__ ushort Bs[128 * 32];
    const int t = threadIdx.x;
    const int w = t >> 6, lane = t & 63;
    const int wr = w >> 1, wc = w & 1;
    const int rowBase = blockIdx.x * 128;
    const int colBase = blockIdx.y * 128;
    const int srow = lane >> 2;          // 0..15 within a 16-row chunk
    const int scol = (lane & 3) * 8;     // k-offset 0,8,16,24

    f32x4 acc[4][4] = {};

    for (int kt = 0; kt < 256; kt += 32) {
        __syncthreads();
#pragma unroll
        for (int c = 0; c < 2; ++c) {
            const int chunk = w * 2 + c;
            const int r = chunk * 16 + srow;
            GLOAD_LDS16(A + (size_t)(rowBase + r) * 256 + kt + scol, As + chunk * 512);
            GLOAD_LDS16(Wb + (size_t)(colBase + r) * 256 + kt + scol, Bs + chunk * 512);
        }
        __syncthreads();
        bf16x8 af[4], bfr[4];
#pragma unroll
        for (int m = 0; m < 4; ++m) {
            const int r = wr * 64 + m * 16 + (lane & 15);
            af[m] = *reinterpret_cast<const bf16x8*>(&As[r * 32 + (lane >> 4) * 8]);
        }
#pragma unroll
        for (int n = 0; n < 4; ++n) {
            const int c2 = wc * 64 + n * 16 + (lane & 15);
            bfr[n] = *reinterpret_cast<const bf16x8*>(&Bs[c2 * 32 + (lane >> 4) * 8]);
        }
#pragma unroll
        for (int m = 0; m < 4; ++m)
#pragma unroll
            for (int n = 0; n < 4; ++n)
                acc[m][n] = __builtin_amdgcn_mfma_f32_16x16x32_bf16(af[m], bfr[n], acc[m][n], 0, 0, 0);
    }

#pragma unroll
    for (int m = 0; m < 4; ++m)
#pragma unroll
        for (int n = 0; n < 4; ++n)
#pragma unroll
            for (int j = 0; j < 4; ++j) {
                const int row = rowBase + wr * 64 + m * 16 + (lane >> 4) * 4 + j;
                const int col = colBase + wc * 64 + n * 16 + (lane & 15);
                float v = acc[m][n][j];
                if (MODE == 0) {
                    ((float*)Yv)[(size_t)row * 256 + col] = elu1(v + bscal[row]);
                } else if (MODE == 1) {
                    ((ushort*)Yv)[(size_t)row * 256 + col] = f2bf(elu1(v));
                } else if (MODE == 2) {
                    ((ushort*)Yv)[(size_t)row * 256 + col] = f2bf(elu1(v + bvec[col]));
                } else {
                    ((float*)Yv)[(size_t)row * 256 + col] = v + bvec[col];
                }
            }
}

// ---------------- kv[b,h,m,d] = sum_n v*k ; ksum[b,h,d] = sum_n k (bf16 in) --------
__global__ __launch_bounds__(256) void k_kvsum(const ushort* __restrict__ kmat,
                                               const ushort* __restrict__ vmat,
                                               float* __restrict__ kv,
                                               float* __restrict__ ksum) {
    const int bh = blockIdx.x;
    const int b = bh >> 3, h = bh & 7;
    const int CH = gridDim.y;
    const int rows = N_ / CH;
    const int tok0 = b * N_ + blockIdx.y * rows;
    __shared__ float kt_[64][32];
    __shared__ float vt_[64][32];
    const int t = threadIdx.x;
    const int m = t >> 3;
    const int lvec = (t & 7) * 4;
    float4 acc = {0.f, 0.f, 0.f, 0.f};
    float4 sk = {0.f, 0.f, 0.f, 0.f};
    for (int r0 = 0; r0 < rows; r0 += 64) {
        __syncthreads();
#pragma unroll
        for (int half = 0; half < 2; ++half) {
            const int rr = (t >> 3) + half * 32;
            const size_t g = (size_t)(tok0 + r0 + rr) * D_ + h * HD_ + lvec;
            const ushort4 ku = *(const ushort4*)(kmat + g);
            const ushort4 vu = *(const ushort4*)(vmat + g);
            kt_[rr][lvec + 0] = bf2f(ku.x); kt_[rr][lvec + 1] = bf2f(ku.y);
            kt_[rr][lvec + 2] = bf2f(ku.z); kt_[rr][lvec + 3] = bf2f(ku.w);
            vt_[rr][lvec + 0] = bf2f(vu.x); vt_[rr][lvec + 1] = bf2f(vu.y);
            vt_[rr][lvec + 2] = bf2f(vu.z); vt_[rr][lvec + 3] = bf2f(vu.w);
        }
        __syncthreads();
#pragma unroll 4
        for (int r = 0; r < 64; ++r) {
            const float vv = vt_[r][m];
            const float4 kk = *(const float4*)&kt_[r][lvec];
            acc.x = fmaf(vv, kk.x, acc.x);
            acc.y = fmaf(vv, kk.y, acc.y);
            acc.z = fmaf(vv, kk.z, acc.z);
            acc.w = fmaf(vv, kk.w, acc.w);
            sk.x += kk.x; sk.y += kk.y; sk.z += kk.z; sk.w += kk.w;
        }
    }
    float* kvp = kv + ((size_t)bh * HD_ + m) * HD_ + lvec;
    atomicAdd(kvp + 0, acc.x);
    atomicAdd(kvp + 1, acc.y);
    atomicAdd(kvp + 2, acc.z);
    atomicAdd(kvp + 3, acc.w);
    if (m == 0) {
        float* kp = ksum + (size_t)bh * HD_ + lvec;
        atomicAdd(kp + 0, sk.x);
        atomicAdd(kp + 1, sk.y);
        atomicAdd(kp + 2, sk.z);
        atomicAdd(kp + 3, sk.w);
    }
}

// ---------------- attn (bf16 out) ----------------
__global__ __launch_bounds__(256) void k_attn(const float* __restrict__ q,
                                              const float* __restrict__ kv,
                                              const float* __restrict__ ksum,
                                              ushort* __restrict__ attn) {
    const int tok = blockIdx.x;
    const int b = tok >> 12;
    const int t = threadIdx.x;
    __shared__ float qs[256];
    qs[t] = q[(size_t)tok * D_ + t];
    __syncthreads();
    const int h = t >> 5, m = t & 31;
    const float* kvp = kv + ((size_t)(b * H_ + h) * HD_ + m) * HD_;
    const float* ksp = ksum + (size_t)(b * H_ + h) * HD_;
    float dot = 0.f, zden = 0.f;
    bool allz = true;
#pragma unroll
    for (int d = 0; d < HD_; ++d) {
        const float qd = qs[h * HD_ + d];
        dot = fmaf(qd, kvp[d], dot);
        zden = fmaf(qd, ksp[d], zden);
        allz = allz && (qd == 0.f);
    }
    const float val = allz ? 0.f : dot / (zden + EPSF);
    attn[(size_t)tok * D_ + t] = f2bf(val);
}

extern "C" void kernel_launch(void* const* d_in, const int* in_sizes, int n_in,
                              void* d_out, int out_size, void* d_ws, size_t ws_size,
                              hipStream_t stream) {
    const float* x     = (const float*)d_in[0];
    const float* prior = (const float*)d_in[1];
    const float* Wq    = (const float*)d_in[2];
    const float* Wk    = (const float*)d_in[3];
    const float* Wv    = (const float*)d_in[4];
    const float* bv    = (const float*)d_in[5];
    const float* Wo    = (const float*)d_in[6];
    const float* bo    = (const float*)d_in[7];
    float* out = (float*)d_out;

    // workspace layout
    char* w8 = (char*)d_ws;
    float* bias   = (float*)w8;                                   // 64 KB
    float* qb     = (float*)(w8 + 65536);                         // 16 MB fp32
    ushort* xb    = (ushort*)(w8 + 65536 + (size_t)TOKENS * D_ * 4);
    ushort* kb    = xb + (size_t)TOKENS * D_;
    ushort* vb    = kb + (size_t)TOKENS * D_;
    ushort* attnb = vb + (size_t)TOKENS * D_;
    ushort* wqb   = attnb + (size_t)TOKENS * D_;                  // 4 x 65536 bf16
    ushort* wkb   = wqb + 65536;
    ushort* wvb   = wkb + 65536;
    ushort* wob   = wvb + 65536;
    float* kvb    = (float*)(wqb + 4 * 65536);
    float* ksb    = kvb + 32768;

    // converts
    k_cvt<<<(TOKENS * D_ / 8 + 255) / 256, 256, 0, stream>>>(x, xb, TOKENS * D_ / 8);
    k_cvt_w<<<128, 256, 0, stream>>>(Wq, Wk, Wv, Wo, wqb);

    k_bias<<<TOKENS, 256, 0, stream>>>(prior, bias);

    dim3 gg(TOKENS / 128, 2);
    k_mfma_gemm<0><<<gg, 256, 0, stream>>>(xb, wqb, nullptr, bias, qb);
    k_mfma_gemm<1><<<gg, 256, 0, stream>>>(xb, wkb, nullptr, nullptr, kb);
    k_mfma_gemm<2><<<gg, 256, 0, stream>>>(xb, wvb, bv, nullptr, vb);

    hipMemsetAsync(kvb, 0, (32768 + 1024) * sizeof(float), stream);
    k_kvsum<<<dim3(32, 8), 256, 0, stream>>>(kb, vb, kvb, ksb);

    k_attn<<<TOKENS, 256, 0, stream>>>(qb, kvb, ksb, attnb);

    k_mfma_gemm<3><<<gg, 256, 0, stream>>>(attnb, wob, bo, nullptr, out);
}